// Round 2
// baseline (64.349 us; speedup 1.0000x reference)
//
#include <hip/hip_runtime.h>

#define NN    4096      // nodes
#define DD    256       // feature dim (= H*HID)
#define NH    4         // heads
#define HIDD  64        // per-head hidden
#define NE    131072    // edges
#define WPR   (NN/32)   // 128 u32 words per adjacency bitmask row
#define SLOPE 0.2f
#define GR    8         // rows per block in GEMM
#define CAP   1024      // max supported degree (Poisson(32) max over 4096 rows << 1024)

// ---------------------------------------------------------------- adjacency
__global__ __launch_bounds__(256) void build_adj_kernel(
    const int* __restrict__ edges, unsigned int* __restrict__ adj) {
    int t = blockIdx.x * 256 + threadIdx.x;
    if (t < NE) {
        int r = edges[t * 3 + 0];
        int c = edges[t * 3 + 1];
        atomicOr(&adj[r * WPR + (c >> 5)], 1u << (c & 31));
    } else if (t < NE + NN) {
        int i = t - NE;
        atomicOr(&adj[i * WPR + (i >> 5)], 1u << (i & 31));
    }
}

// ---------------------------------------------------------------- Wh = X @ W
__global__ __launch_bounds__(256) void gemm_wh_kernel(
    const float* __restrict__ in, const float* __restrict__ W,
    float* __restrict__ Wh) {
    __shared__ float in_s[GR][DD];
    int row0 = blockIdx.x * GR;
    int t = threadIdx.x;
    #pragma unroll
    for (int r = 0; r < GR; ++r) in_s[r][t] = in[(row0 + r) * DD + t];
    __syncthreads();
    float acc[GR];
    #pragma unroll
    for (int r = 0; r < GR; ++r) acc[r] = 0.f;
    #pragma unroll 4
    for (int k = 0; k < DD; ++k) {
        float w = W[k * DD + t];          // coalesced; W L2-resident after warmup
        #pragma unroll
        for (int r = 0; r < GR; ++r) acc[r] = fmaf(in_s[r][k], w, acc[r]);
    }
    #pragma unroll
    for (int r = 0; r < GR; ++r) Wh[(row0 + r) * DD + t] = acc[r];
}

// ---------------------------------------------------------------- e1,e2 logits
__global__ __launch_bounds__(256) void e12_kernel(
    const float* __restrict__ Wh, const float* __restrict__ att,
    float* __restrict__ e1, float* __restrict__ e2) {
    int i = blockIdx.x;
    int t = threadIdx.x;
    int h = t >> 6, f = t & 63;
    float v  = Wh[i * DD + h * HIDD + f];
    float p1 = v * att[f];
    float p2 = v * att[HIDD + f];
    #pragma unroll
    for (int off = 32; off; off >>= 1) {
        p1 += __shfl_xor(p1, off);
        p2 += __shfl_xor(p2, off);
    }
    if (f == 0) {
        e1[i * NH + h] = p1;
        e2[i * NH + h] = p2;
    }
}

// ---------------------------------------------------------------- per-row GAT
__global__ __launch_bounds__(256) void gat_row_kernel(
    const unsigned int* __restrict__ adj, const float* __restrict__ Wh,
    const float* __restrict__ e1, const float* __restrict__ e2,
    float* __restrict__ out) {
    int i    = blockIdx.x;
    int t    = threadIdx.x;
    int lane = t & 63, wid = t >> 6;

    __shared__ int   nbr[CAP];
    __shared__ float wgt[CAP][NH];
    __shared__ int   cnt;
    __shared__ float wred[4][NH];

    if (t == 0) cnt = 0;
    __syncthreads();

    // ---- pass 1: scan bitmask row, collect neighbors + e2, track per-head max
    float m2[NH] = {-1e30f, -1e30f, -1e30f, -1e30f};
    if (t < WPR) {
        unsigned int bits = adj[i * WPR + t];
        while (bits) {
            int b = __ffs(bits) - 1;
            bits &= bits - 1;
            int j = t * 32 + b;
            int d = atomicAdd(&cnt, 1);
            if (d < CAP) {
                nbr[d] = j;
                float4 ev = *(const float4*)(e2 + j * NH);
                wgt[d][0] = ev.x; wgt[d][1] = ev.y;
                wgt[d][2] = ev.z; wgt[d][3] = ev.w;
                m2[0] = fmaxf(m2[0], ev.x); m2[1] = fmaxf(m2[1], ev.y);
                m2[2] = fmaxf(m2[2], ev.z); m2[3] = fmaxf(m2[3], ev.w);
            }
        }
    }
    // block-level max reduce (wave shuffle, then 4 wave partials via LDS)
    #pragma unroll
    for (int off = 32; off; off >>= 1) {
        #pragma unroll
        for (int h = 0; h < NH; ++h) m2[h] = fmaxf(m2[h], __shfl_xor(m2[h], off));
    }
    if (lane == 0) {
        #pragma unroll
        for (int h = 0; h < NH; ++h) wred[wid][h] = m2[h];
    }
    __syncthreads();

    float Mh[NH], e1v[NH];
    #pragma unroll
    for (int h = 0; h < NH; ++h) {
        float mx = fmaxf(fmaxf(wred[0][h], wred[1][h]),
                         fmaxf(wred[2][h], wred[3][h]));
        e1v[h] = e1[i * NH + h];
        float s = e1v[h] + mx;               // lrelu is monotone -> max commutes
        Mh[h]   = (s >= 0.f) ? s : SLOPE * s;
    }
    int cn = cnt;
    if (cn > CAP) cn = CAP;

    // ---- weights + per-head Z
    float zl[NH] = {0.f, 0.f, 0.f, 0.f};
    for (int d = t; d < cn; d += 256) {
        #pragma unroll
        for (int h = 0; h < NH; ++h) {
            float s = e1v[h] + wgt[d][h];
            s = (s >= 0.f) ? s : SLOPE * s;
            float w = expf(s - Mh[h]);
            wgt[d][h] = w;
            zl[h] += w;
        }
    }
    #pragma unroll
    for (int off = 32; off; off >>= 1) {
        #pragma unroll
        for (int h = 0; h < NH; ++h) zl[h] += __shfl_xor(zl[h], off);
    }
    __syncthreads();               // all wred reads (max) + wgt writes done
    if (lane == 0) {
        #pragma unroll
        for (int h = 0; h < NH; ++h) wred[wid][h] = zl[h];
    }
    __syncthreads();

    float Zf[NH];
    #pragma unroll
    for (int h = 0; h < NH; ++h)
        Zf[h] = wred[0][h] + wred[1][h] + wred[2][h] + wred[3][h];

    // ---- gather: thread (h=wid, f=lane) accumulates over neighbors
    int h = wid, f = lane;
    float acc = 0.f;
    for (int d = 0; d < cn; ++d) {
        // wgt[d][h], nbr[d]: LDS broadcast. Wh row: 256B coalesced per wave.
        acc = fmaf(wgt[d][h], Wh[nbr[d] * DD + h * HIDD + f], acc);
    }
    float r = acc / Zf[h];
    out[i * DD + t] = (r > 0.f) ? r : (expf(r) - 1.f);   // ELU(alpha=1)
}

// ---------------------------------------------------------------- launcher
extern "C" void kernel_launch(void* const* d_in, const int* in_sizes, int n_in,
                              void* d_out, int out_size, void* d_ws, size_t ws_size,
                              hipStream_t stream) {
    const float* inp   = (const float*)d_in[0];
    const int*   edges = (const int*)d_in[1];
    // d_in[2] = num_node (scalar, constant 4096) — unused
    const float* W     = (const float*)d_in[3];
    const float* att   = (const float*)d_in[4];
    float*       out   = (float*)d_out;

    char* ws = (char*)d_ws;
    float*        Wh  = (float*)(ws);                               // 4 MB
    float*        e1  = (float*)(ws + 4u * 1024 * 1024);            // 64 KB
    float*        e2  = (float*)(ws + 4u * 1024 * 1024 + 65536);    // 64 KB
    unsigned int* adj = (unsigned int*)(ws + 4u * 1024 * 1024 + 2 * 65536); // 2 MB

    (void)hipMemsetAsync(adj, 0, (size_t)NN * WPR * sizeof(unsigned int), stream);
    build_adj_kernel<<<(NE + NN + 255) / 256, 256, 0, stream>>>(edges, adj);
    gemm_wh_kernel<<<NN / GR, 256, 0, stream>>>(inp, W, Wh);
    e12_kernel<<<NN, 256, 0, stream>>>(Wh, att, e1, e2);
    gat_row_kernel<<<NN, 256, 0, stream>>>(adj, Wh, e1, e2, out);
}

// Round 3
// 62.647 us; speedup vs baseline: 1.0272x; 1.0272x over previous
//
#include <hip/hip_runtime.h>

#define NN    4096      // nodes
#define DD    256       // feature dim (= H*HID)
#define NH    4         // heads
#define HIDD  64        // per-head hidden
#define NE    131072    // edges
#define WPR   (NN/32)   // 128 u32 words per adjacency bitmask row
#define SLOPE 0.2f
#define GR    8         // rows per block in GEMM
#define CAP   1024      // max supported degree (mean deg ~33, Poisson tail << 1024)

// ---------------------------------------------------------------- zero adj
// 512 blocks * 256 threads * 16B = 2 MB exactly. Replaces the runtime's
// fillBuffer (which ran at 50 GB/s / 42 us for this size).
__global__ __launch_bounds__(256) void zero_adj_kernel(uint4* __restrict__ adj4) {
    int t = blockIdx.x * 256 + threadIdx.x;
    adj4[t] = uint4{0u, 0u, 0u, 0u};
}

// ---------------------------------------------------------------- adjacency
__global__ __launch_bounds__(256) void build_adj_kernel(
    const int* __restrict__ edges, unsigned int* __restrict__ adj) {
    int t = blockIdx.x * 256 + threadIdx.x;
    if (t < NE) {
        int r = edges[t * 3 + 0];
        int c = edges[t * 3 + 1];
        atomicOr(&adj[r * WPR + (c >> 5)], 1u << (c & 31));
    } else if (t < NE + NN) {
        int i = t - NE;
        atomicOr(&adj[i * WPR + (i >> 5)], 1u << (i & 31));
    }
}

// ---------------------------------------------------------------- Wh = X @ W  (+ fused e1/e2)
// Wave w of the block covers cols [64w, 64w+64) == head w; the e1/e2 dots
// are wave shuffle reductions over the acc registers.
__global__ __launch_bounds__(256) void gemm_wh_e12_kernel(
    const float* __restrict__ in, const float* __restrict__ W,
    const float* __restrict__ att,
    float* __restrict__ Wh, float* __restrict__ e1, float* __restrict__ e2) {
    __shared__ float in_s[GR][DD];
    int row0 = blockIdx.x * GR;
    int t    = threadIdx.x;
    int lane = t & 63, h = t >> 6;
    #pragma unroll
    for (int r = 0; r < GR; ++r) in_s[r][t] = in[(row0 + r) * DD + t];
    __syncthreads();
    float acc[GR];
    #pragma unroll
    for (int r = 0; r < GR; ++r) acc[r] = 0.f;
    #pragma unroll 4
    for (int k = 0; k < DD; ++k) {
        float w = W[k * DD + t];          // coalesced; W is 256 KB, L2-resident
        #pragma unroll
        for (int r = 0; r < GR; ++r) acc[r] = fmaf(in_s[r][k], w, acc[r]);
    }
    float a1 = att[lane];                 // att[:64]  for this head-feature f=lane
    float a2 = att[HIDD + lane];          // att[64:]
    #pragma unroll
    for (int r = 0; r < GR; ++r) Wh[(row0 + r) * DD + t] = acc[r];
    #pragma unroll
    for (int r = 0; r < GR; ++r) {
        float p1 = acc[r] * a1;
        float p2 = acc[r] * a2;
        #pragma unroll
        for (int off = 32; off; off >>= 1) {
            p1 += __shfl_xor(p1, off);
            p2 += __shfl_xor(p2, off);
        }
        if (lane == 0) {
            e1[(row0 + r) * NH + h] = p1;
            e2[(row0 + r) * NH + h] = p2;
        }
    }
}

// ---------------------------------------------------------------- per-row GAT
__global__ __launch_bounds__(256) void gat_row_kernel(
    const unsigned int* __restrict__ adj, const float* __restrict__ Wh,
    const float* __restrict__ e1, const float* __restrict__ e2,
    float* __restrict__ out) {
    int i    = blockIdx.x;
    int t    = threadIdx.x;
    int lane = t & 63, wid = t >> 6;

    __shared__ int   nbr[CAP];
    __shared__ float wgt[CAP][NH];
    __shared__ int   cnt;
    __shared__ float wred[4][NH];

    if (t == 0) cnt = 0;
    __syncthreads();

    // ---- pass 1: scan bitmask row, collect neighbors + e2, track per-head max
    float m2[NH] = {-1e30f, -1e30f, -1e30f, -1e30f};
    if (t < WPR) {
        unsigned int bits = adj[i * WPR + t];
        while (bits) {
            int b = __ffs(bits) - 1;
            bits &= bits - 1;
            int j = t * 32 + b;
            int d = atomicAdd(&cnt, 1);
            if (d < CAP) {
                nbr[d] = j;
                float4 ev = *(const float4*)(e2 + j * NH);
                wgt[d][0] = ev.x; wgt[d][1] = ev.y;
                wgt[d][2] = ev.z; wgt[d][3] = ev.w;
                m2[0] = fmaxf(m2[0], ev.x); m2[1] = fmaxf(m2[1], ev.y);
                m2[2] = fmaxf(m2[2], ev.z); m2[3] = fmaxf(m2[3], ev.w);
            }
        }
    }
    // block-level max reduce (wave shuffle, then 4 wave partials via LDS)
    #pragma unroll
    for (int off = 32; off; off >>= 1) {
        #pragma unroll
        for (int h = 0; h < NH; ++h) m2[h] = fmaxf(m2[h], __shfl_xor(m2[h], off));
    }
    if (lane == 0) {
        #pragma unroll
        for (int h = 0; h < NH; ++h) wred[wid][h] = m2[h];
    }
    __syncthreads();

    float Mh[NH], e1v[NH];
    #pragma unroll
    for (int h = 0; h < NH; ++h) {
        float mx = fmaxf(fmaxf(wred[0][h], wred[1][h]),
                         fmaxf(wred[2][h], wred[3][h]));
        e1v[h] = e1[i * NH + h];
        float s = e1v[h] + mx;               // lrelu is monotone -> max commutes
        Mh[h]   = (s >= 0.f) ? s : SLOPE * s;
    }
    int cn = cnt;
    if (cn > CAP) cn = CAP;

    // ---- weights + per-head Z
    float zl[NH] = {0.f, 0.f, 0.f, 0.f};
    for (int d = t; d < cn; d += 256) {
        #pragma unroll
        for (int h = 0; h < NH; ++h) {
            float s = e1v[h] + wgt[d][h];
            s = (s >= 0.f) ? s : SLOPE * s;
            float w = expf(s - Mh[h]);
            wgt[d][h] = w;
            zl[h] += w;
        }
    }
    #pragma unroll
    for (int off = 32; off; off >>= 1) {
        #pragma unroll
        for (int h = 0; h < NH; ++h) zl[h] += __shfl_xor(zl[h], off);
    }
    __syncthreads();               // all wred reads (max) + wgt writes done
    if (lane == 0) {
        #pragma unroll
        for (int h = 0; h < NH; ++h) wred[wid][h] = zl[h];
    }
    __syncthreads();

    float Zf[NH];
    #pragma unroll
    for (int h = 0; h < NH; ++h)
        Zf[h] = wred[0][h] + wred[1][h] + wred[2][h] + wred[3][h];

    // ---- gather: thread (h=wid, f=lane) accumulates over neighbors
    int h = wid, f = lane;
    float acc = 0.f;
    for (int d = 0; d < cn; ++d) {
        // wgt[d][h], nbr[d]: LDS broadcast. Wh row: 256B coalesced per wave.
        acc = fmaf(wgt[d][h], Wh[nbr[d] * DD + h * HIDD + f], acc);
    }
    float r = acc / Zf[h];
    out[i * DD + t] = (r > 0.f) ? r : (expf(r) - 1.f);   // ELU(alpha=1)
}

// ---------------------------------------------------------------- launcher
extern "C" void kernel_launch(void* const* d_in, const int* in_sizes, int n_in,
                              void* d_out, int out_size, void* d_ws, size_t ws_size,
                              hipStream_t stream) {
    const float* inp   = (const float*)d_in[0];
    const int*   edges = (const int*)d_in[1];
    // d_in[2] = num_node (scalar, constant 4096) — unused
    const float* W     = (const float*)d_in[3];
    const float* att   = (const float*)d_in[4];
    float*       out   = (float*)d_out;

    char* ws = (char*)d_ws;
    float*        Wh  = (float*)(ws);                               // 4 MB
    float*        e1  = (float*)(ws + 4u * 1024 * 1024);            // 64 KB
    float*        e2  = (float*)(ws + 4u * 1024 * 1024 + 65536);    // 64 KB
    unsigned int* adj = (unsigned int*)(ws + 4u * 1024 * 1024 + 2 * 65536); // 2 MB

    zero_adj_kernel<<<512, 256, 0, stream>>>((uint4*)adj);
    build_adj_kernel<<<(NE + NN + 255) / 256, 256, 0, stream>>>(edges, adj);
    gemm_wh_e12_kernel<<<NN / GR, 256, 0, stream>>>(inp, W, att, Wh, e1, e2);
    gat_row_kernel<<<NN, 256, 0, stream>>>(adj, Wh, e1, e2, out);
}